// Round 1
// baseline (271.716 us; speedup 1.0000x reference)
//
#include <hip/hip_runtime.h>

// Problem constants
#define BB     128
#define TOPK   32
#define MN     64
#define NODES  258        // MAX_NODES + 2
#define HD     128
#define ED     128
#define G3     384        // 3*H
#define NREL   400
#define NROWS_NODE (BB * NODES)   // 33024
#define NROWS_ENT  (BB * TOPK)    // 4096

// ---------------------------------------------------------------------------
// Copy node_embeddings -> out (float4, fully coalesced). 4,227,072 floats.
__global__ void copy_emb(const float4* __restrict__ src, float4* __restrict__ dst) {
    int i = blockIdx.x * blockDim.x + threadIdx.x;   // grid sized exactly
    dst[i] = src[i];
}

// ---------------------------------------------------------------------------
// Transpose W_ih (384x256) -> wt_ih (256x384) and W_hh (384x128) -> wt_hh (128x384)
// so GEMM reads of W are lane-coalesced. 147,456 elements total (tiny).
__global__ void transpose_w(const float* __restrict__ W_ih, const float* __restrict__ W_hh,
                            float* __restrict__ wt_ih, float* __restrict__ wt_hh) {
    int i = blockIdx.x * blockDim.x + threadIdx.x;
    if (i < 256 * 384) {
        int e = i / 384, g = i % 384;
        wt_ih[i] = W_ih[g * 256 + e];
    } else {
        int j = i - 256 * 384;   // < 128*384 by grid sizing
        int k = j / 384, g = j % 384;
        wt_hh[j] = W_hh[g * 128 + k];
    }
}

// ---------------------------------------------------------------------------
// C[row][g] = sum_k A[src(row)][k] * WT[k][g] + bias[g]
// K = 128 fixed, 384 output cols, 16 rows per block (384 threads, 1 col each).
// A-tile staged in LDS (broadcast reads in k-loop); WT reads coalesced;
// 16 FMA per WT load.
__global__ void gemm384(const float* __restrict__ A, const int* __restrict__ gidx,
                        const float* __restrict__ WT, const float* __restrict__ bias,
                        float* __restrict__ C, int nrows) {
    __shared__ float As[16][128];
    const int row0 = blockIdx.x * 16;
    const int tid  = threadIdx.x;     // 0..383
    // stage 16x128 A tile (coalesced; gather via gidx if provided)
    for (int i = tid; i < 16 * 128; i += 384) {
        int r = i >> 7, k = i & 127;
        int row = row0 + r;
        long src = (long)(gidx ? gidx[row] : row) * 128;
        As[r][k] = A[src + k];
    }
    __syncthreads();
    float acc[16];
#pragma unroll
    for (int r = 0; r < 16; ++r) acc[r] = 0.f;
    const int g = tid;
#pragma unroll 4
    for (int k = 0; k < 128; ++k) {
        float w = WT[k * 384 + g];
#pragma unroll
        for (int r = 0; r < 16; ++r) acc[r] += w * As[r][k];
    }
    float bv = bias ? bias[g] : 0.f;
#pragma unroll
    for (int r = 0; r < 16; ++r)
        C[(long)(row0 + r) * 384 + g] = acc[r] + bv;
}

// ---------------------------------------------------------------------------
// Main GRU + masked mean + last-wins scatter. One block per (b,t), 128 threads
// (one per h). Loops only over valid neighbors (m < num).
__global__ void gru_agg(const float* __restrict__ node_emb,   // (B,258,128) original
                        const float* __restrict__ gi_rel,     // (400,384)
                        const float* __restrict__ gi_ent,     // (4096,384) = W@ent + b_ih
                        const float* __restrict__ gh_node,    // (B*258,384) = W_hh@h + b_hh
                        const int*   __restrict__ aim_nodes,  // (B,32)
                        const int*   __restrict__ neighbors,  // (B,32,64,2)
                        const int*   __restrict__ nb_num,     // (B,32)
                        float* __restrict__ out)              // (B,258,128)
{
    const int bt = blockIdx.x;            // 0..4095
    const int b  = bt >> 5, t = bt & 31;
    const int h  = threadIdx.x;           // 0..127

    const float ge_r = gi_ent[bt * 384 + h];
    const float ge_z = gi_ent[bt * 384 + 128 + h];
    const float ge_n = gi_ent[bt * 384 + 256 + h];

    int num = nb_num[bt];
    if (num > MN) num = MN;

    const int*   nb  = neighbors + (long)bt * MN * 2;
    const float* ghb = gh_node  + (long)b * NODES * 384;
    const float* heb = node_emb + (long)b * NODES * 128;

    float acc = 0.f;
    for (int m = 0; m < num; ++m) {
        const int node = nb[2 * m];
        const int rel  = nb[2 * m + 1];
        const float* gr = gi_rel + rel * 384;
        const float* gh = ghb + node * 384;
        float i_r = ge_r + gr[h];
        float i_z = ge_z + gr[128 + h];
        float i_n = ge_n + gr[256 + h];
        float h_r = gh[h];
        float h_z = gh[128 + h];
        float h_n = gh[256 + h];
        float hv  = heb[node * 128 + h];
        float r = 1.f / (1.f + __expf(-(i_r + h_r)));
        float z = 1.f / (1.f + __expf(-(i_z + h_z)));
        float xt = i_n + r * h_n;
        xt = fminf(10.f, fmaxf(-10.f, xt));          // tanh saturation guard
        float e2 = __expf(2.f * xt);
        float n  = (e2 - 1.f) / (e2 + 1.f);
        acc += (1.f - z) * n + z * hv;
    }
    const float denom = (num > 0) ? (float)num : 1.f;
    const float upd = acc / denom;

    // numpy fancy-assign semantics: last occurrence of a duplicate aim node wins
    const int myaim = aim_nodes[bt];
    bool write = true;
    for (int t2 = t + 1; t2 < TOPK; ++t2) {
        if (aim_nodes[b * TOPK + t2] == myaim) { write = false; break; }
    }
    if (write) out[((long)b * NODES + myaim) * 128 + h] = upd;
}

// ---------------------------------------------------------------------------
extern "C" void kernel_launch(void* const* d_in, const int* in_sizes, int n_in,
                              void* d_out, int out_size, void* d_ws, size_t ws_size,
                              hipStream_t stream) {
    const float* node_emb = (const float*)d_in[0];   // (128,258,128)
    const float* ent_tab  = (const float*)d_in[1];   // (40000,128)
    const float* rel_tab  = (const float*)d_in[2];   // (400,128)
    const float* W_ih     = (const float*)d_in[3];   // (384,256)
    const float* W_hh     = (const float*)d_in[4];   // (384,128)
    const float* b_ih     = (const float*)d_in[5];   // (384)
    const float* b_hh     = (const float*)d_in[6];   // (384)
    const int* aim_nodes  = (const int*)d_in[7];     // (128,32)
    const int* aim_ent    = (const int*)d_in[8];     // (128,32)
    const int* neighbors  = (const int*)d_in[9];     // (128,32,64,2)
    const int* nb_num     = (const int*)d_in[10];    // (128,32)
    float* out = (float*)d_out;

    // workspace layout (floats); total 14,555,136 floats = 58.2 MB
    float* ws      = (float*)d_ws;
    float* wt_ih   = ws;                       // 256*384
    float* wt_hh   = wt_ih  + 256 * 384;       // 128*384
    float* gi_rel  = wt_hh  + 128 * 384;       // 400*384
    float* gi_ent  = gi_rel + NREL * 384;      // 4096*384
    float* gh_node = gi_ent + NROWS_ENT * 384; // 33024*384

    // 1) copy full node table into output (scatter overwrites aim rows later)
    hipLaunchKernelGGL(copy_emb, dim3((BB * NODES * HD / 4) / 256), dim3(256), 0, stream,
                       (const float4*)node_emb, (float4*)out);
    // 2) transpose weights for coalesced GEMM reads
    hipLaunchKernelGGL(transpose_w, dim3((256 * 384 + 128 * 384) / 256), dim3(256), 0, stream,
                       W_ih, W_hh, wt_ih, wt_hh);
    // 3) gi_rel[r] = W_ih[:,E:] @ relation_table[r]           (400 rows)
    hipLaunchKernelGGL(gemm384, dim3(NREL / 16), dim3(384), 0, stream,
                       rel_tab, (const int*)nullptr, wt_ih + 128 * 384,
                       (const float*)nullptr, gi_rel, NREL);
    // 4) gi_ent[b,t] = W_ih[:,:E] @ ent[aim_entities] + b_ih  (4096 rows, gathered)
    hipLaunchKernelGGL(gemm384, dim3(NROWS_ENT / 16), dim3(384), 0, stream,
                       ent_tab, aim_ent, wt_ih, b_ih, gi_ent, NROWS_ENT);
    // 5) gh_node[b,n] = W_hh @ node_emb[b,n] + b_hh           (33024 rows)
    hipLaunchKernelGGL(gemm384, dim3(NROWS_NODE / 16), dim3(384), 0, stream,
                       node_emb, (const int*)nullptr, wt_hh, b_hh, gh_node, NROWS_NODE);
    // 6) GRU gates + masked mean + last-wins scatter
    hipLaunchKernelGGL(gru_agg, dim3(BB * TOPK), dim3(128), 0, stream,
                       node_emb, gi_rel, gi_ent, gh_node,
                       aim_nodes, neighbors, nb_num, out);
}

// Round 2
// 180.517 us; speedup vs baseline: 1.5052x; 1.5052x over previous
//
#include <hip/hip_runtime.h>

// Problem constants
#define BB     128
#define TOPK   32
#define MN     64
#define NODES  258          // MAX_NODES + 2
#define HD     128
#define G3     384          // 3*H
#define NREL   400
#define SEG1_OFF 448        // rel rows padded 400 -> 448 (x64)
#define SEG2_OFF 4544       // 448 + 4096
#define NROWS_TOT 37568     // 448 + 4096 + 33024  (x64)

typedef __bf16 bf16x8 __attribute__((ext_vector_type(8)));
typedef float  f32x4  __attribute__((ext_vector_type(4)));

__device__ inline unsigned short f2bf(float f) {
    unsigned u = __float_as_uint(f);
    u = (u + 0x7fff + ((u >> 16) & 1)) >> 16;   // round-to-nearest-even
    return (unsigned short)u;
}
__device__ inline float bf2f(unsigned short s) {
    return __uint_as_float(((unsigned)s) << 16);
}
__device__ inline float fsig(float x) {        // sigmoid via v_exp/v_rcp
    float e = __builtin_amdgcn_exp2f(-1.442695041f * x);
    return __builtin_amdgcn_rcpf(1.f + e);
}
__device__ inline float ftanh(float x) {
    x = fminf(15.f, fmaxf(-15.f, x));
    float e = __builtin_amdgcn_exp2f(2.885390082f * x);   // e^(2x)
    return (e - 1.f) * __builtin_amdgcn_rcpf(e + 1.f);
}

// ---------------------------------------------------------------------------
// Build unified bf16 A matrix [rel(448 incl pad) | gathered ent(4096) | node(33024)]
// and simultaneously copy node_embeddings -> out (the scatter base).
__global__ __launch_bounds__(256) void pack_all(
        const float* __restrict__ node_emb, const float* __restrict__ ent_tab,
        const float* __restrict__ rel_tab, const int* __restrict__ aim_ent,
        unsigned short* __restrict__ A, float* __restrict__ out) {
    int i = blockIdx.x * 256 + threadIdx.x;     // grid sized exactly
    int row = i >> 7, k = i & 127;
    float v;
    if (row < NREL)            v = rel_tab[i];
    else if (row < SEG1_OFF)   v = 0.f;                                   // pad
    else if (row < SEG2_OFF)   v = ent_tab[(size_t)aim_ent[row - SEG1_OFF] * 128 + k];
    else {
        int n = row - SEG2_OFF;                 // b*258 + node, linear
        v = node_emb[(size_t)n * 128 + k];
        out[(size_t)n * 128 + k] = v;           // fused copy
    }
    A[i] = f2bf(v);
}

// ---------------------------------------------------------------------------
// Pack weights per segment as Wt[n][k] bf16 (seg0: W_ih[:,E:], seg1: W_ih[:,:E],
// seg2: W_hh) plus per-segment bias (0 / b_ih / b_hh).
__global__ __launch_bounds__(256) void pack_w(
        const float* __restrict__ W_ih, const float* __restrict__ W_hh,
        const float* __restrict__ b_ih, const float* __restrict__ b_hh,
        unsigned short* __restrict__ Wpack, float* __restrict__ biasb) {
    int i = blockIdx.x * 256 + threadIdx.x;     // 147456 total
    int s = i / 49152, r = i % 49152;
    int n = r >> 7, k = r & 127;
    float v;
    if (s == 0)      v = W_ih[n * 256 + 128 + k];
    else if (s == 1) v = W_ih[n * 256 + k];
    else             v = W_hh[n * 128 + k];
    Wpack[i] = f2bf(v);
    if (i < 3 * 384) {
        int s2 = i / 384, g = i % 384;
        biasb[i] = (s2 == 0) ? 0.f : (s2 == 1 ? b_ih[g] : b_hh[g]);
    }
}

// ---------------------------------------------------------------------------
// G[row][g] = A[row] @ Wt_seg + bias_seg, bf16 MFMA 16x16x32.
// Block = 4 waves, 64-row stripe (16 rows/wave); wave loops 24 col tiles.
// A-frag: lane reads A[row0+(l&15)][kb*32+(l>>4)*8 ..+7]; B-frag mirrored on Wt[n][k].
// D: row=(l>>4)*4+i, col=l&15.
__global__ __launch_bounds__(256) void mfma_gemm(
        const unsigned short* __restrict__ A, const unsigned short* __restrict__ Wpack,
        const float* __restrict__ biasb, unsigned short* __restrict__ G) {
    const int w = threadIdx.x >> 6, lane = threadIdx.x & 63;
    const int row0 = blockIdx.x * 64 + w * 16;
    const int seg  = (row0 < SEG1_OFF) ? 0 : (row0 < SEG2_OFF ? 1 : 2);
    const unsigned short* Wt = Wpack + (size_t)seg * 384 * 128;
    const int limit = (seg == 0) ? NREL : NROWS_TOT;   // skip pad-row stores

    const int koff  = (lane >> 4) << 3;      // quad*8
    const int arow  = row0 + (lane & 15);
    const int rbase = row0 + ((lane >> 4) << 2);
    bf16x8 a[4];
#pragma unroll
    for (int kb = 0; kb < 4; ++kb)
        a[kb] = *reinterpret_cast<const bf16x8*>(A + (size_t)arow * 128 + kb * 32 + koff);

#pragma unroll 2
    for (int t = 0; t < 24; ++t) {
        const int bcol = t * 16 + (lane & 15);
        bf16x8 bf[4];
#pragma unroll
        for (int kb = 0; kb < 4; ++kb)
            bf[kb] = *reinterpret_cast<const bf16x8*>(Wt + (size_t)bcol * 128 + kb * 32 + koff);
        f32x4 acc = {0.f, 0.f, 0.f, 0.f};
#pragma unroll
        for (int kb = 0; kb < 4; ++kb)
            acc = __builtin_amdgcn_mfma_f32_16x16x32_bf16(a[kb], bf[kb], acc, 0, 0, 0);
        const float bv = biasb[seg * 384 + bcol];
#pragma unroll
        for (int i = 0; i < 4; ++i) {
            int grow = rbase + i;
            if (grow < limit) G[(size_t)grow * 384 + bcol] = f2bf(acc[i] + bv);
        }
    }
}

// ---------------------------------------------------------------------------
// GRU gates + masked mean + last-wins scatter. One block per (b,t), 128 threads.
__global__ __launch_bounds__(128) void gru_agg(
        const float* __restrict__ node_emb, const unsigned short* __restrict__ G,
        const int* __restrict__ aim_nodes, const int* __restrict__ neighbors,
        const int* __restrict__ nb_num, float* __restrict__ out) {
    const int bt = blockIdx.x;
    const int b = bt >> 5, t = bt & 31;
    const int h = threadIdx.x;

    // numpy fancy-assign: last duplicate wins; skip all work if overwritten later
    const int myaim = aim_nodes[bt];
    for (int t2 = t + 1; t2 < TOPK; ++t2)
        if (aim_nodes[b * TOPK + t2] == myaim) return;   // uniform across block

    __shared__ int2 nbs[MN];
    if (h < MN) nbs[h] = ((const int2*)(neighbors + (size_t)bt * MN * 2))[h];
    __syncthreads();

    const size_t erow = (size_t)(SEG1_OFF + bt) * 384;
    const float ge_r = bf2f(G[erow + h]);
    const float ge_z = bf2f(G[erow + 128 + h]);
    const float ge_n = bf2f(G[erow + 256 + h]);

    int num = nb_num[bt];
    num = (num < 0) ? 0 : (num > MN ? MN : num);

    const unsigned short* ghb = G + (size_t)(SEG2_OFF + b * NODES) * 384;
    const float* heb = node_emb + (size_t)b * NODES * 128;

    float acc = 0.f;
    int m = 0;
    for (; m + 4 <= num; m += 4) {
        float gr_r[4], gr_z[4], gr_n[4], h_r[4], h_z[4], h_n[4], hv[4];
#pragma unroll
        for (int j = 0; j < 4; ++j) {          // issue all 28 loads first
            int2 p = nbs[m + j];
            const unsigned short* gr = G + (size_t)p.y * 384;
            const unsigned short* gh = ghb + (size_t)p.x * 384;
            gr_r[j] = bf2f(gr[h]); gr_z[j] = bf2f(gr[128 + h]); gr_n[j] = bf2f(gr[256 + h]);
            h_r[j]  = bf2f(gh[h]); h_z[j]  = bf2f(gh[128 + h]); h_n[j]  = bf2f(gh[256 + h]);
            hv[j]   = heb[(size_t)p.x * 128 + h];
        }
#pragma unroll
        for (int j = 0; j < 4; ++j) {
            float r = fsig(ge_r + gr_r[j] + h_r[j]);
            float z = fsig(ge_z + gr_z[j] + h_z[j]);
            float n = ftanh(ge_n + gr_n[j] + r * h_n[j]);
            acc += (1.f - z) * n + z * hv[j];
        }
    }
    for (; m < num; ++m) {
        int2 p = nbs[m];
        const unsigned short* gr = G + (size_t)p.y * 384;
        const unsigned short* gh = ghb + (size_t)p.x * 384;
        float r = fsig(ge_r + bf2f(gr[h]) + bf2f(gh[h]));
        float z = fsig(ge_z + bf2f(gr[128 + h]) + bf2f(gh[128 + h]));
        float n = ftanh(ge_n + bf2f(gr[256 + h]) + r * bf2f(gh[256 + h]));
        acc += (1.f - z) * n + z * heb[(size_t)p.x * 128 + h];
    }
    const float denom = (num > 0) ? (float)num : 1.f;
    out[((size_t)b * NODES + myaim) * 128 + h] = acc * __builtin_amdgcn_rcpf(denom);
}

// ---------------------------------------------------------------------------
extern "C" void kernel_launch(void* const* d_in, const int* in_sizes, int n_in,
                              void* d_out, int out_size, void* d_ws, size_t ws_size,
                              hipStream_t stream) {
    const float* node_emb = (const float*)d_in[0];
    const float* ent_tab  = (const float*)d_in[1];
    const float* rel_tab  = (const float*)d_in[2];
    const float* W_ih     = (const float*)d_in[3];
    const float* W_hh     = (const float*)d_in[4];
    const float* b_ih     = (const float*)d_in[5];
    const float* b_hh     = (const float*)d_in[6];
    const int* aim_nodes  = (const int*)d_in[7];
    const int* aim_ent    = (const int*)d_in[8];
    const int* neighbors  = (const int*)d_in[9];
    const int* nb_num     = (const int*)d_in[10];
    float* out = (float*)d_out;

    // ws layout (all 16B-aligned): G bf16 (28.85 MB) | A bf16 (9.62 MB) |
    // Wpack bf16 (288 KB) | bias f32 (4.6 KB)  => ~38.8 MB total
    unsigned short* G     = (unsigned short*)d_ws;
    unsigned short* A     = G + (size_t)NROWS_TOT * 384;
    unsigned short* Wpack = A + (size_t)NROWS_TOT * 128;
    float*          biasb = (float*)(Wpack + 3 * 384 * 128);

    hipLaunchKernelGGL(pack_all, dim3(NROWS_TOT * 128 / 256), dim3(256), 0, stream,
                       node_emb, ent_tab, rel_tab, aim_ent, A, out);
    hipLaunchKernelGGL(pack_w, dim3(3 * 384 * 128 / 256), dim3(256), 0, stream,
                       W_ih, W_hh, b_ih, b_hh, Wpack, biasb);
    hipLaunchKernelGGL(mfma_gemm, dim3(NROWS_TOT / 64), dim3(256), 0, stream,
                       A, Wpack, biasb, G);
    hipLaunchKernelGGL(gru_agg, dim3(BB * TOPK), dim3(128), 0, stream,
                       node_emb, G, aim_nodes, neighbors, nb_num, out);
}

// Round 3
// 151.260 us; speedup vs baseline: 1.7964x; 1.1934x over previous
//
#include <hip/hip_runtime.h>

// Problem constants
#define BB     128
#define TOPK   32
#define MN     64
#define NODES  258          // MAX_NODES + 2
#define HD     128
#define G3     384          // 3*H
#define NREL   400
#define SEG1_OFF 448        // rel rows padded 400 -> 448
#define SEG2_OFF 4544       // 448 + 4096
#define NROWS_TOT 37568     // 448 + 4096 + 33024
#define ROWPAD   37632      // padded to x128 for 128-row blocks
#define COLSPLIT 3

typedef __bf16 bf16x8 __attribute__((ext_vector_type(8)));
typedef float  f32x4  __attribute__((ext_vector_type(4)));

__device__ inline unsigned short f2bf(float f) {
    unsigned u = __float_as_uint(f);
    u = (u + 0x7fff + ((u >> 16) & 1)) >> 16;   // round-to-nearest-even
    return (unsigned short)u;
}
__device__ inline float bf2f(unsigned short s) {
    return __uint_as_float(((unsigned)s) << 16);
}
__device__ inline float fsig(float x) {
    float e = __builtin_amdgcn_exp2f(-1.442695041f * x);
    return __builtin_amdgcn_rcpf(1.f + e);
}
__device__ inline float ftanh(float x) {
    x = fminf(15.f, fmaxf(-15.f, x));
    float e = __builtin_amdgcn_exp2f(2.885390082f * x);
    return (e - 1.f) * __builtin_amdgcn_rcpf(e + 1.f);
}

// ---------------------------------------------------------------------------
// Build unified bf16 A matrix [rel(448) | gathered ent(4096) | node(33024) | pad(64)]
// vectorized x8, with fused node_emb -> out copy.
__global__ __launch_bounds__(256) void pack_all(
        const float* __restrict__ node_emb, const float* __restrict__ ent_tab,
        const float* __restrict__ rel_tab, const int* __restrict__ aim_ent,
        unsigned short* __restrict__ A, float* __restrict__ out) {
    int i = blockIdx.x * 256 + threadIdx.x;     // ROWPAD*16 threads
    int row = i >> 4, kc = (i & 15) << 3;       // 8-element chunk
    float4 v0 = {0.f,0.f,0.f,0.f}, v1 = {0.f,0.f,0.f,0.f};
    if (row < NREL) {
        const float4* p = (const float4*)(rel_tab + (size_t)row * 128 + kc);
        v0 = p[0]; v1 = p[1];
    } else if (row < SEG1_OFF) {
        // zero pad
    } else if (row < SEG2_OFF) {
        const float* e = ent_tab + (size_t)aim_ent[row - SEG1_OFF] * 128 + kc;
        v0 = ((const float4*)e)[0]; v1 = ((const float4*)e)[1];
    } else if (row < NROWS_TOT) {
        int n = row - SEG2_OFF;
        const float4* p = (const float4*)(node_emb + (size_t)n * 128 + kc);
        v0 = p[0]; v1 = p[1];
        float4* o = (float4*)(out + (size_t)n * 128 + kc);
        o[0] = v0; o[1] = v1;                  // fused copy to scatter base
    }
    union { unsigned short s[8]; uint4 v; } u;
    u.s[0]=f2bf(v0.x); u.s[1]=f2bf(v0.y); u.s[2]=f2bf(v0.z); u.s[3]=f2bf(v0.w);
    u.s[4]=f2bf(v1.x); u.s[5]=f2bf(v1.y); u.s[6]=f2bf(v1.z); u.s[7]=f2bf(v1.w);
    *(uint4*)(A + (size_t)row * 128 + kc) = u.v;
}

// ---------------------------------------------------------------------------
// Pack weights per segment as Wt[n][k] bf16 + per-segment bias.
__global__ __launch_bounds__(256) void pack_w(
        const float* __restrict__ W_ih, const float* __restrict__ W_hh,
        const float* __restrict__ b_ih, const float* __restrict__ b_hh,
        unsigned short* __restrict__ Wpack, float* __restrict__ biasb) {
    int i = blockIdx.x * 256 + threadIdx.x;     // 147456 total
    int s = i / 49152, r = i % 49152;
    int n = r >> 7, k = r & 127;
    float v;
    if (s == 0)      v = W_ih[n * 256 + 128 + k];
    else if (s == 1) v = W_ih[n * 256 + k];
    else             v = W_hh[n * 128 + k];
    Wpack[i] = f2bf(v);
    if (i < 3 * 384) {
        int s2 = i / 384, g = i % 384;
        biasb[i] = (s2 == 0) ? 0.f : (s2 == 1 ? b_ih[g] : b_hh[g]);
    }
}

// ---------------------------------------------------------------------------
// G = A @ Wt_seg + bias. Block = 4 waves x 32 rows = 128 rows, 128 cols (1/3 of 384).
// Per block: stage the 32 KB W-slice into LDS in MFMA-fragment lane order
// (reader ds_read_b128 is lane-linear -> conflict-free); inner loop has no
// global loads at all. Wave: 2 row-tiles x 8 col-tiles, 8 MFMA per 4 ds_reads.
__global__ __launch_bounds__(256) void mfma_gemm(
        const unsigned short* __restrict__ A, const unsigned short* __restrict__ Wpack,
        const float* __restrict__ biasb, unsigned short* __restrict__ G) {
    __shared__ __align__(16) unsigned short Bs[128 * 128];   // 32 KB
    const int tid = threadIdx.x;
    const int w = tid >> 6, lane = tid & 63;
    const int rb = blockIdx.x / COLSPLIT, cs = blockIdx.x % COLSPLIT;
    const int row0 = rb * 128 + w * 32;        // wave's 32 rows
    const int seg  = (row0 < SEG1_OFF) ? 0 : (row0 < SEG2_OFF ? 1 : 2);
    const int limit = (seg == 0) ? NREL : NROWS_TOT;
    const int colbase = cs * 128;
    const unsigned short* Wt = Wpack + (size_t)seg * 49152 + (size_t)colbase * 128;

    // Stage: LDS chunk dst (16B) holds the B-frag piece for (tile tt, kb, quad qq,
    // col cc): Wt[(tt*16+cc)*128 + kb*32 + qq*8 .. +7]. LDS writes are lane-linear
    // (conflict-free); the transpose lands on the once-per-block global read.
#pragma unroll
    for (int ii = 0; ii < 8; ++ii) {
        int dst = ii * 256 + tid;              // 0..2047
        int g = dst >> 6, rem = dst & 63;
        int qq = rem >> 4, cc = rem & 15;
        int tt = g >> 2, kbb = g & 3;
        uint4 v = *(const uint4*)(Wt + (size_t)(tt * 16 + cc) * 128 + kbb * 32 + qq * 8);
        *(uint4*)(Bs + dst * 8) = v;
    }

    const int q = lane >> 4, c = lane & 15;
    const int koff = q << 3;
    bf16x8 a0[4], a1[4];
    {
        const unsigned short* Ar0 = A + (size_t)(row0 + c) * 128 + koff;
        const unsigned short* Ar1 = Ar0 + 16 * 128;
#pragma unroll
        for (int kb = 0; kb < 4; ++kb) {
            a0[kb] = *(const bf16x8*)(Ar0 + kb * 32);
            a1[kb] = *(const bf16x8*)(Ar1 + kb * 32);
        }
    }
    float bv[8];
#pragma unroll
    for (int t = 0; t < 8; ++t)
        bv[t] = biasb[seg * 384 + colbase + t * 16 + c];

    __syncthreads();

    const int r0 = row0 + q * 4, r1 = r0 + 16;
#pragma unroll 2
    for (int t = 0; t < 8; ++t) {
        bf16x8 bf[4];
#pragma unroll
        for (int kb = 0; kb < 4; ++kb)
            bf[kb] = *(const bf16x8*)(Bs + (size_t)((t * 4 + kb) * 64 + lane) * 8);
        f32x4 acc0 = {0.f,0.f,0.f,0.f}, acc1 = {0.f,0.f,0.f,0.f};
#pragma unroll
        for (int kb = 0; kb < 4; ++kb) {
            acc0 = __builtin_amdgcn_mfma_f32_16x16x32_bf16(a0[kb], bf[kb], acc0, 0, 0, 0);
            acc1 = __builtin_amdgcn_mfma_f32_16x16x32_bf16(a1[kb], bf[kb], acc1, 0, 0, 0);
        }
        const int gc = colbase + t * 16 + c;
#pragma unroll
        for (int i2 = 0; i2 < 4; ++i2) {
            if (r0 + i2 < limit) G[(size_t)(r0 + i2) * 384 + gc] = f2bf(acc0[i2] + bv[t]);
            if (r1 + i2 < limit) G[(size_t)(r1 + i2) * 384 + gc] = f2bf(acc1[i2] + bv[t]);
        }
    }
}

// ---------------------------------------------------------------------------
// GRU gates + masked mean + last-wins scatter. One block per (b,t), 128 threads.
__global__ __launch_bounds__(128) void gru_agg(
        const float* __restrict__ node_emb, const unsigned short* __restrict__ G,
        const int* __restrict__ aim_nodes, const int* __restrict__ neighbors,
        const int* __restrict__ nb_num, float* __restrict__ out) {
    const int bt = blockIdx.x;
    const int b = bt >> 5, t = bt & 31;
    const int h = threadIdx.x;

    const int myaim = aim_nodes[bt];
    for (int t2 = t + 1; t2 < TOPK; ++t2)
        if (aim_nodes[b * TOPK + t2] == myaim) return;   // last duplicate wins

    __shared__ int2 nbs[MN];
    if (h < MN) nbs[h] = ((const int2*)(neighbors + (size_t)bt * MN * 2))[h];
    __syncthreads();

    const size_t erow = (size_t)(SEG1_OFF + bt) * 384;
    const float ge_r = bf2f(G[erow + h]);
    const float ge_z = bf2f(G[erow + 128 + h]);
    const float ge_n = bf2f(G[erow + 256 + h]);

    int num = nb_num[bt];
    num = (num < 0) ? 0 : (num > MN ? MN : num);

    const unsigned short* ghb = G + (size_t)(SEG2_OFF + b * NODES) * 384;
    const float* heb = node_emb + (size_t)b * NODES * 128;

    float acc = 0.f;
    int m = 0;
    for (; m + 4 <= num; m += 4) {
        float gr_r[4], gr_z[4], gr_n[4], h_r[4], h_z[4], h_n[4], hv[4];
#pragma unroll
        for (int j = 0; j < 4; ++j) {
            int2 p = nbs[m + j];
            const unsigned short* gr = G + (size_t)p.y * 384;
            const unsigned short* gh = ghb + (size_t)p.x * 384;
            gr_r[j] = bf2f(gr[h]); gr_z[j] = bf2f(gr[128 + h]); gr_n[j] = bf2f(gr[256 + h]);
            h_r[j]  = bf2f(gh[h]); h_z[j]  = bf2f(gh[128 + h]); h_n[j]  = bf2f(gh[256 + h]);
            hv[j]   = heb[(size_t)p.x * 128 + h];
        }
#pragma unroll
        for (int j = 0; j < 4; ++j) {
            float r = fsig(ge_r + gr_r[j] + h_r[j]);
            float z = fsig(ge_z + gr_z[j] + h_z[j]);
            float n = ftanh(ge_n + gr_n[j] + r * h_n[j]);
            acc += (1.f - z) * n + z * hv[j];
        }
    }
    for (; m < num; ++m) {
        int2 p = nbs[m];
        const unsigned short* gr = G + (size_t)p.y * 384;
        const unsigned short* gh = ghb + (size_t)p.x * 384;
        float r = fsig(ge_r + bf2f(gr[h]) + bf2f(gh[h]));
        float z = fsig(ge_z + bf2f(gr[128 + h]) + bf2f(gh[128 + h]));
        float n = ftanh(ge_n + bf2f(gr[256 + h]) + r * bf2f(gh[256 + h]));
        acc += (1.f - z) * n + z * heb[(size_t)p.x * 128 + h];
    }
    const float denom = (num > 0) ? (float)num : 1.f;
    out[((size_t)b * NODES + myaim) * 128 + h] = acc * __builtin_amdgcn_rcpf(denom);
}

// ---------------------------------------------------------------------------
extern "C" void kernel_launch(void* const* d_in, const int* in_sizes, int n_in,
                              void* d_out, int out_size, void* d_ws, size_t ws_size,
                              hipStream_t stream) {
    const float* node_emb = (const float*)d_in[0];
    const float* ent_tab  = (const float*)d_in[1];
    const float* rel_tab  = (const float*)d_in[2];
    const float* W_ih     = (const float*)d_in[3];
    const float* W_hh     = (const float*)d_in[4];
    const float* b_ih     = (const float*)d_in[5];
    const float* b_hh     = (const float*)d_in[6];
    const int* aim_nodes  = (const int*)d_in[7];
    const int* aim_ent    = (const int*)d_in[8];
    const int* neighbors  = (const int*)d_in[9];
    const int* nb_num     = (const int*)d_in[10];
    float* out = (float*)d_out;

    // ws: G bf16 28.85 MB | A bf16 9.63 MB (ROWPAD rows) | Wpack 288 KB | bias
    unsigned short* G     = (unsigned short*)d_ws;
    unsigned short* A     = G + (size_t)NROWS_TOT * 384;
    unsigned short* Wpack = A + (size_t)ROWPAD * 128;
    float*          biasb = (float*)(Wpack + 3 * 384 * 128);

    hipLaunchKernelGGL(pack_all, dim3(ROWPAD * 16 / 256), dim3(256), 0, stream,
                       node_emb, ent_tab, rel_tab, aim_ent, A, out);
    hipLaunchKernelGGL(pack_w, dim3(3 * 384 * 128 / 256), dim3(256), 0, stream,
                       W_ih, W_hh, b_ih, b_hh, Wpack, biasb);
    hipLaunchKernelGGL(mfma_gemm, dim3((ROWPAD / 128) * COLSPLIT), dim3(256), 0, stream,
                       A, Wpack, biasb, G);
    hipLaunchKernelGGL(gru_agg, dim3(BB * TOPK), dim3(128), 0, stream,
                       node_emb, G, aim_nodes, neighbors, nb_num, out);
}

// Round 4
// 151.182 us; speedup vs baseline: 1.7973x; 1.0005x over previous
//
#include <hip/hip_runtime.h>

// Problem constants
#define BB     128
#define TOPK   32
#define MN     64
#define NODES  258          // MAX_NODES + 2
#define HD     128
#define G3     384          // 3*H
#define NREL   400
#define SEG1_OFF 512        // rel rows padded 400 -> 512 (x128: seg-uniform GEMM blocks)
#define SEG2_OFF 4608       // 512 + 4096
#define NROWS_TOT 37632     // 512 + 4096 + 33024  (x128 exactly)
#define ROWPAD   37632
#define COLSPLIT 3

typedef __bf16 bf16x8 __attribute__((ext_vector_type(8)));
typedef float  f32x4  __attribute__((ext_vector_type(4)));

__device__ inline unsigned short f2bf(float f) {
    unsigned u = __float_as_uint(f);
    u = (u + 0x7fff + ((u >> 16) & 1)) >> 16;   // round-to-nearest-even
    return (unsigned short)u;
}
__device__ inline float bf2f(unsigned short s) {
    return __uint_as_float(((unsigned)s) << 16);
}
__device__ inline float fsig(float x) {
    float e = __builtin_amdgcn_exp2f(-1.442695041f * x);
    return __builtin_amdgcn_rcpf(1.f + e);
}
__device__ inline float ftanh(float x) {
    x = fminf(15.f, fmaxf(-15.f, x));
    float e = __builtin_amdgcn_exp2f(2.885390082f * x);
    return (e - 1.f) * __builtin_amdgcn_rcpf(e + 1.f);
}

// ---------------------------------------------------------------------------
// Build unified bf16 A matrix [rel(512 incl pad) | gathered ent(4096) | node(33024)]
// vectorized x8; fused node_emb -> out copy and bf16 node_emb copy (NE16).
__global__ __launch_bounds__(256) void pack_all(
        const float* __restrict__ node_emb, const float* __restrict__ ent_tab,
        const float* __restrict__ rel_tab, const int* __restrict__ aim_ent,
        unsigned short* __restrict__ A, unsigned short* __restrict__ NE16,
        float* __restrict__ out) {
    int i = blockIdx.x * 256 + threadIdx.x;     // ROWPAD*16 threads
    int row = i >> 4, kc = (i & 15) << 3;       // 8-element chunk
    float4 v0 = {0.f,0.f,0.f,0.f}, v1 = {0.f,0.f,0.f,0.f};
    bool isnode = false;
    int n = 0;
    if (row < NREL) {
        const float4* p = (const float4*)(rel_tab + (size_t)row * 128 + kc);
        v0 = p[0]; v1 = p[1];
    } else if (row < SEG1_OFF) {
        // zero pad
    } else if (row < SEG2_OFF) {
        const float* e = ent_tab + (size_t)aim_ent[row - SEG1_OFF] * 128 + kc;
        v0 = ((const float4*)e)[0]; v1 = ((const float4*)e)[1];
    } else {
        isnode = true;
        n = row - SEG2_OFF;                     // b*258 + node, linear
        const float4* p = (const float4*)(node_emb + (size_t)n * 128 + kc);
        v0 = p[0]; v1 = p[1];
        float4* o = (float4*)(out + (size_t)n * 128 + kc);
        o[0] = v0; o[1] = v1;                   // fused copy to scatter base
    }
    union { unsigned short s[8]; uint4 v; } u;
    u.s[0]=f2bf(v0.x); u.s[1]=f2bf(v0.y); u.s[2]=f2bf(v0.z); u.s[3]=f2bf(v0.w);
    u.s[4]=f2bf(v1.x); u.s[5]=f2bf(v1.y); u.s[6]=f2bf(v1.z); u.s[7]=f2bf(v1.w);
    *(uint4*)(A + (size_t)row * 128 + kc) = u.v;
    if (isnode) *(uint4*)(NE16 + (size_t)n * 128 + kc) = u.v;  // bf16 hv table
}

// ---------------------------------------------------------------------------
// Pack weights per segment as Wt[n][k] bf16 + per-segment bias.
__global__ __launch_bounds__(256) void pack_w(
        const float* __restrict__ W_ih, const float* __restrict__ W_hh,
        const float* __restrict__ b_ih, const float* __restrict__ b_hh,
        unsigned short* __restrict__ Wpack, float* __restrict__ biasb) {
    int i = blockIdx.x * 256 + threadIdx.x;     // 147456 total
    int s = i / 49152, r = i % 49152;
    int n = r >> 7, k = r & 127;
    float v;
    if (s == 0)      v = W_ih[n * 256 + 128 + k];
    else if (s == 1) v = W_ih[n * 256 + k];
    else             v = W_hh[n * 128 + k];
    Wpack[i] = f2bf(v);
    if (i < 3 * 384) {
        int s2 = i / 384, g = i % 384;
        biasb[i] = (s2 == 0) ? 0.f : (s2 == 1 ? b_ih[g] : b_hh[g]);
    }
}

// ---------------------------------------------------------------------------
// G = A @ Wt_seg + bias. Block = 4 waves x 32 rows = 128 rows (seg-uniform by
// construction: seg boundaries are 128-aligned), 128 cols (1/3 of 384).
// W-slice staged once into LDS in MFMA-fragment lane order (conflict-free
// ds_read_b128 in the loop); zero global loads in the inner loop.
__global__ __launch_bounds__(256) void mfma_gemm(
        const unsigned short* __restrict__ A, const unsigned short* __restrict__ Wpack,
        const float* __restrict__ biasb, unsigned short* __restrict__ G) {
    __shared__ __align__(16) unsigned short Bs[128 * 128];   // 32 KB
    const int tid = threadIdx.x;
    const int w = tid >> 6, lane = tid & 63;
    const int rb = blockIdx.x / COLSPLIT, cs = blockIdx.x % COLSPLIT;
    const int brow = rb * 128;                 // block rows: seg-uniform
    const int row0 = brow + w * 32;            // wave's 32 rows
    const int seg  = (brow < SEG1_OFF) ? 0 : (brow < SEG2_OFF ? 1 : 2);
    const int limit = (seg == 0) ? NREL : NROWS_TOT;
    const int colbase = cs * 128;
    const unsigned short* Wt = Wpack + (size_t)seg * 49152 + (size_t)colbase * 128;

    // Stage: chunk d holds Wt[(tt*16+cc)*128 + kbb*32 + qq*8 ..+7] where
    // d = (tt*4+kbb)*64 + qq*16 + cc  — exactly the reader's lane-linear order.
#pragma unroll
    for (int ii = 0; ii < 8; ++ii) {
        int dst = ii * 256 + tid;              // 0..2047
        int g = dst >> 6, rem = dst & 63;
        int qq = rem >> 4, cc = rem & 15;
        int tt = g >> 2, kbb = g & 3;
        uint4 v = *(const uint4*)(Wt + (size_t)(tt * 16 + cc) * 128 + kbb * 32 + qq * 8);
        *(uint4*)(Bs + dst * 8) = v;
    }

    const int q = lane >> 4, c = lane & 15;
    const int koff = q << 3;
    bf16x8 a0[4], a1[4];
    {
        const unsigned short* Ar0 = A + (size_t)(row0 + c) * 128 + koff;
        const unsigned short* Ar1 = Ar0 + 16 * 128;
#pragma unroll
        for (int kb = 0; kb < 4; ++kb) {
            a0[kb] = *(const bf16x8*)(Ar0 + kb * 32);
            a1[kb] = *(const bf16x8*)(Ar1 + kb * 32);
        }
    }
    float bv[8];
#pragma unroll
    for (int t = 0; t < 8; ++t)
        bv[t] = biasb[seg * 384 + colbase + t * 16 + c];

    __syncthreads();

    const int r0 = row0 + q * 4, r1 = r0 + 16;
#pragma unroll 2
    for (int t = 0; t < 8; ++t) {
        bf16x8 bf[4];
#pragma unroll
        for (int kb = 0; kb < 4; ++kb)
            bf[kb] = *(const bf16x8*)(Bs + (size_t)((t * 4 + kb) * 64 + lane) * 8);
        f32x4 acc0 = {0.f,0.f,0.f,0.f}, acc1 = {0.f,0.f,0.f,0.f};
#pragma unroll
        for (int kb = 0; kb < 4; ++kb) {
            acc0 = __builtin_amdgcn_mfma_f32_16x16x32_bf16(a0[kb], bf[kb], acc0, 0, 0, 0);
            acc1 = __builtin_amdgcn_mfma_f32_16x16x32_bf16(a1[kb], bf[kb], acc1, 0, 0, 0);
        }
        const int gc = colbase + t * 16 + c;
#pragma unroll
        for (int i2 = 0; i2 < 4; ++i2) {
            if (r0 + i2 < limit) G[(size_t)(r0 + i2) * 384 + gc] = f2bf(acc0[i2] + bv[t]);
            if (r1 + i2 < limit) G[(size_t)(r1 + i2) * 384 + gc] = f2bf(acc1[i2] + bv[t]);
        }
    }
}

// ---------------------------------------------------------------------------
// GRU gates + masked mean + last-wins scatter. Block = 512 threads per (b,t):
// 4 m-groups x 128 h-lanes, m-strided; partial sums LDS-reduced. Serial depth
// per group: <=8 paired iterations (14 loads in flight each).
__global__ __launch_bounds__(512) void gru_agg(
        const unsigned short* __restrict__ NE16, const unsigned short* __restrict__ G,
        const int* __restrict__ aim_nodes, const int* __restrict__ neighbors,
        const int* __restrict__ nb_num, float* __restrict__ out) {
    const int bt = blockIdx.x;
    const int b = bt >> 5, t = bt & 31;
    const int tid = threadIdx.x;
    const int h = tid & 127, j = tid >> 7;    // m-group 0..3

    // numpy fancy-assign: last duplicate wins (uniform across block)
    const int myaim = aim_nodes[bt];
    for (int t2 = t + 1; t2 < TOPK; ++t2)
        if (aim_nodes[b * TOPK + t2] == myaim) return;

    __shared__ int2 nbs[MN];
    __shared__ float part[4][128];
    if (tid < MN) nbs[tid] = ((const int2*)(neighbors + (size_t)bt * MN * 2))[tid];
    __syncthreads();

    const size_t erow = (size_t)(SEG1_OFF + bt) * 384;
    const float ge_r = bf2f(G[erow + h]);
    const float ge_z = bf2f(G[erow + 128 + h]);
    const float ge_n = bf2f(G[erow + 256 + h]);

    int num = nb_num[bt];
    num = (num < 0) ? 0 : (num > MN ? MN : num);

    const unsigned short* ghb = G + (size_t)(SEG2_OFF + b * NODES) * 384;
    const unsigned short* heb = NE16 + (size_t)b * NODES * 128;

    float acc = 0.f;
    int m = j;
    for (; m + 4 < num; m += 8) {             // pair: m and m+4
        int2 p0 = nbs[m], p1 = nbs[m + 4];
        const unsigned short* gr0 = G + (size_t)p0.y * 384;
        const unsigned short* gh0 = ghb + (size_t)p0.x * 384;
        const unsigned short* gr1 = G + (size_t)p1.y * 384;
        const unsigned short* gh1 = ghb + (size_t)p1.x * 384;
        float ar0 = bf2f(gr0[h]), az0 = bf2f(gr0[128+h]), an0 = bf2f(gr0[256+h]);
        float hr0 = bf2f(gh0[h]), hz0 = bf2f(gh0[128+h]), hn0 = bf2f(gh0[256+h]);
        float hv0 = bf2f(heb[(size_t)p0.x * 128 + h]);
        float ar1 = bf2f(gr1[h]), az1 = bf2f(gr1[128+h]), an1 = bf2f(gr1[256+h]);
        float hr1 = bf2f(gh1[h]), hz1 = bf2f(gh1[128+h]), hn1 = bf2f(gh1[256+h]);
        float hv1 = bf2f(heb[(size_t)p1.x * 128 + h]);
        float r0 = fsig(ge_r + ar0 + hr0);
        float z0 = fsig(ge_z + az0 + hz0);
        float n0 = ftanh(ge_n + an0 + r0 * hn0);
        acc += (1.f - z0) * n0 + z0 * hv0;
        float r1 = fsig(ge_r + ar1 + hr1);
        float z1 = fsig(ge_z + az1 + hz1);
        float n1 = ftanh(ge_n + an1 + r1 * hn1);
        acc += (1.f - z1) * n1 + z1 * hv1;
    }
    if (m < num) {
        int2 p = nbs[m];
        const unsigned short* gr = G + (size_t)p.y * 384;
        const unsigned short* gh = ghb + (size_t)p.x * 384;
        float r = fsig(ge_r + bf2f(gr[h]) + bf2f(gh[h]));
        float z = fsig(ge_z + bf2f(gr[128 + h]) + bf2f(gh[128 + h]));
        float n = ftanh(ge_n + bf2f(gr[256 + h]) + r * bf2f(gh[256 + h]));
        acc += (1.f - z) * n + z * bf2f(heb[(size_t)p.x * 128 + h]);
    }
    part[j][h] = acc;
    __syncthreads();
    if (j == 0) {
        float s = part[0][h] + part[1][h] + part[2][h] + part[3][h];
        const float denom = (num > 0) ? (float)num : 1.f;
        out[((size_t)b * NODES + myaim) * 128 + h] = s * __builtin_amdgcn_rcpf(denom);
    }
}

// ---------------------------------------------------------------------------
extern "C" void kernel_launch(void* const* d_in, const int* in_sizes, int n_in,
                              void* d_out, int out_size, void* d_ws, size_t ws_size,
                              hipStream_t stream) {
    const float* node_emb = (const float*)d_in[0];
    const float* ent_tab  = (const float*)d_in[1];
    const float* rel_tab  = (const float*)d_in[2];
    const float* W_ih     = (const float*)d_in[3];
    const float* W_hh     = (const float*)d_in[4];
    const float* b_ih     = (const float*)d_in[5];
    const float* b_hh     = (const float*)d_in[6];
    const int* aim_nodes  = (const int*)d_in[7];
    const int* aim_ent    = (const int*)d_in[8];
    const int* neighbors  = (const int*)d_in[9];
    const int* nb_num     = (const int*)d_in[10];
    float* out = (float*)d_out;

    // ws: G bf16 28.9 MB | A bf16 9.63 MB | NE16 8.45 MB | Wpack 288 KB | bias
    unsigned short* G     = (unsigned short*)d_ws;
    unsigned short* A     = G + (size_t)NROWS_TOT * 384;
    unsigned short* NE16  = A + (size_t)ROWPAD * 128;
    unsigned short* Wpack = NE16 + (size_t)BB * NODES * 128;
    float*          biasb = (float*)(Wpack + 3 * 384 * 128);

    hipLaunchKernelGGL(pack_all, dim3(ROWPAD * 16 / 256), dim3(256), 0, stream,
                       node_emb, ent_tab, rel_tab, aim_ent, A, NE16, out);
    hipLaunchKernelGGL(pack_w, dim3(3 * 384 * 128 / 256), dim3(256), 0, stream,
                       W_ih, W_hh, b_ih, b_hh, Wpack, biasb);
    hipLaunchKernelGGL(mfma_gemm, dim3((ROWPAD / 128) * COLSPLIT), dim3(256), 0, stream,
                       A, Wpack, biasb, G);
    hipLaunchKernelGGL(gru_agg, dim3(BB * TOPK), dim3(512), 0, stream,
                       NE16, G, aim_nodes, neighbors, nb_num, out);
}